// Round 1
// 1111.077 us; speedup vs baseline: 1.1814x; 1.1814x over previous
//
#include <hip/hip_runtime.h>
#include <hip/hip_bf16.h>
#include <math.h>

#define NN 50000
#define DD 128
#define LLAYERS 3
#define RR 16
#define EE 1600000

typedef unsigned int u32;

__device__ __forceinline__ float bflo(u32 u){ union{u32 i;float f;}a; a.i=u<<16; return a.f; }
__device__ __forceinline__ float bfhi(u32 u){ union{u32 i;float f;}a; a.i=u&0xffff0000u; return a.f; }
__device__ __forceinline__ u32 pack_bf2(float x, float y){
  union{float f;u32 i;}a,b; a.f=x; b.f=y;
  u32 xr = (a.i + 0x7fffu + ((a.i>>16)&1u)) >> 16;
  u32 yr = (b.i + 0x7fffu + ((b.i>>16)&1u)) & 0xffff0000u;
  return (xr & 0xffffu) | yr;
}

// ---------------- CSR build ----------------
__global__ __launch_bounds__(256) void k_hist(const int* __restrict__ rows, int* __restrict__ cnt){
  int e = blockIdx.x*256 + threadIdx.x;
  if (e < EE) atomicAdd(&cnt[rows[e]], 1);
}

__global__ __launch_bounds__(256) void k_scanA(const int* __restrict__ cnt, int* __restrict__ bsum){
  __shared__ int s[256];
  int i = blockIdx.x*256 + threadIdx.x;
  int v = (i < NN) ? cnt[i] : 0;
  s[threadIdx.x] = v; __syncthreads();
  for (int off=128; off>0; off>>=1){
    if (threadIdx.x < off) s[threadIdx.x] += s[threadIdx.x+off];
    __syncthreads();
  }
  if (threadIdx.x==0) bsum[blockIdx.x] = s[0];
}

__global__ __launch_bounds__(256) void k_scanB(int* bsum){
  __shared__ int s[256];
  int t = threadIdx.x;
  int v = bsum[t];
  s[t] = v; __syncthreads();
  for (int off=1; off<256; off<<=1){
    int x = (t>=off) ? s[t-off] : 0; __syncthreads();
    s[t] += x; __syncthreads();
  }
  bsum[t] = s[t] - v; // exclusive block offsets
}

__global__ __launch_bounds__(256) void k_scanC(const int* __restrict__ cnt, const int* __restrict__ bsum,
                        int* __restrict__ row_ptr, int* __restrict__ cursor){
  __shared__ int s[256];
  int t = threadIdx.x; int i = blockIdx.x*256 + t;
  int v = (i<NN)?cnt[i]:0;
  s[t]=v; __syncthreads();
  for (int off=1; off<256; off<<=1){
    int x=(t>=off)?s[t-off]:0; __syncthreads();
    s[t]+=x; __syncthreads();
  }
  if (i<NN){ int e = bsum[blockIdx.x] + s[t]-v; row_ptr[i]=e; cursor[i]=e; }
}

// pack (col, val) into one 8B scattered store (halves scattered lines, one stream load in spmm)
__global__ __launch_bounds__(256) void k_scatter(const int* __restrict__ rows, const int* __restrict__ cols,
                          const float* __restrict__ vals,
                          int* __restrict__ cursor, int2* __restrict__ colval){
  int e = blockIdx.x*256+threadIdx.x;
  if (e<EE){
    int r = rows[e];
    int p = atomicAdd(&cursor[r],1);
    int2 cv; cv.x = cols[e]; cv.y = __float_as_int(vals[e]);
    colval[p] = cv;
  }
}

// ---------------- init: h -> bf16 packed, accumulate z column sums (16 partial slots) ----------------
__global__ __launch_bounds__(256) void k_init(const float4* __restrict__ nf, uint2* __restrict__ hbf,
                                              float* __restrict__ z){
  __shared__ float zp[128];
  int t = threadIdx.x;
  if (t < 128) zp[t] = 0.f;
  float a0=0.f,a1=0.f,a2=0.f,a3=0.f;
  for (int i = blockIdx.x*256 + t; i < NN*DD/4; i += gridDim.x*256){
    float4 v = nf[i];
    uint2 p; p.x = pack_bf2(v.x, v.y); p.y = pack_bf2(v.z, v.w);
    hbf[i] = p;
    a0 += v.x; a1 += v.y; a2 += v.z; a3 += v.w;
  }
  __syncthreads();
  int c = (t*4) & 127;
  atomicAdd(&zp[c],a0); atomicAdd(&zp[c+1],a1); atomicAdd(&zp[c+2],a2); atomicAdd(&zp[c+3],a3);
  __syncthreads();
  if (t < 128) atomicAdd(&z[((blockIdx.x&15)<<7) + t], zp[t]);
}

// transpose gnn_W (L x D x D, row-major [l][j][k]) -> wT [l][k][j]
__global__ __launch_bounds__(256) void k_wT(const float* __restrict__ W, float* __restrict__ wT){
  int idx = blockIdx.x*256+threadIdx.x; // 49152
  int l = idx >> 14; int r = idx & 16383; int k = r >> 7; int j = r & 127;
  wT[(l<<14) + k*128 + j] = W[(l<<14) + j*128 + k];
}

// ---------------- fused layer: SPMM (16-row tile -> LDS) + GEMM + ELU + z colsum + bf16 out ----------
// block = 256 threads = 4 waves; wave wv owns rows i0+wv*4 .. +3 for BOTH phases (a_s rows stay
// within the producing wave; __syncthreads kept for safety, once per block).
__global__ __launch_bounds__(256) void k_layer(const int* __restrict__ row_ptr, const int* __restrict__ cnt,
                       const int2* __restrict__ colval,
                       const u32* __restrict__ hin, const float* __restrict__ wTl,
                       const float* __restrict__ bl,
                       u32* __restrict__ hout, float* __restrict__ z, int last){
  __shared__ float a_s[16*128];
  __shared__ float zp[128];
  int t = threadIdx.x;
  if (t < 128) zp[t] = 0.f;
  int i0 = blockIdx.x * 16;
  int lane = t & 63;
  int wv = t >> 6;                    // wave id 0..3
  int sub = lane >> 4, k = lane & 15; // quarter-wave: 16 lanes x 16B = one 128-feat bf16 row

  // ---- SPMM phase: 4 rows per wave, 8 gathers in flight (2-way unroll x 4 quarter-waves)
  for (int r = 0; r < 4; ++r){
    int row = i0 + wv*4 + r;
    int base = row_ptr[row], n = cnt[row];
    float a0=0,a1=0,a2=0,a3=0,a4=0,a5=0,a6=0,a7=0;
    int p = sub;
    for (; p + 4 < n; p += 8){
      int2 cv0 = colval[base+p];
      int2 cv1 = colval[base+p+4];
      uint4 h0 = *(const uint4*)&hin[((size_t)(u32)cv0.x<<6) + (k<<2)];
      uint4 h1 = *(const uint4*)&hin[((size_t)(u32)cv1.x<<6) + (k<<2)];
      float v0 = __int_as_float(cv0.y);
      float v1 = __int_as_float(cv1.y);
      a0 = fmaf(v0, bflo(h0.x), a0); a1 = fmaf(v0, bfhi(h0.x), a1);
      a2 = fmaf(v0, bflo(h0.y), a2); a3 = fmaf(v0, bfhi(h0.y), a3);
      a4 = fmaf(v0, bflo(h0.z), a4); a5 = fmaf(v0, bfhi(h0.z), a5);
      a6 = fmaf(v0, bflo(h0.w), a6); a7 = fmaf(v0, bfhi(h0.w), a7);
      a0 = fmaf(v1, bflo(h1.x), a0); a1 = fmaf(v1, bfhi(h1.x), a1);
      a2 = fmaf(v1, bflo(h1.y), a2); a3 = fmaf(v1, bfhi(h1.y), a3);
      a4 = fmaf(v1, bflo(h1.z), a4); a5 = fmaf(v1, bfhi(h1.z), a5);
      a6 = fmaf(v1, bflo(h1.w), a6); a7 = fmaf(v1, bfhi(h1.w), a7);
    }
    if (p < n){
      int2 cv = colval[base+p];
      float v = __int_as_float(cv.y);
      uint4 hv = *(const uint4*)&hin[((size_t)(u32)cv.x<<6) + (k<<2)];
      a0 = fmaf(v, bflo(hv.x), a0); a1 = fmaf(v, bfhi(hv.x), a1);
      a2 = fmaf(v, bflo(hv.y), a2); a3 = fmaf(v, bfhi(hv.y), a3);
      a4 = fmaf(v, bflo(hv.z), a4); a5 = fmaf(v, bfhi(hv.z), a5);
      a6 = fmaf(v, bflo(hv.w), a6); a7 = fmaf(v, bfhi(hv.w), a7);
    }
    a0 += __shfl_xor(a0,16); a0 += __shfl_xor(a0,32);
    a1 += __shfl_xor(a1,16); a1 += __shfl_xor(a1,32);
    a2 += __shfl_xor(a2,16); a2 += __shfl_xor(a2,32);
    a3 += __shfl_xor(a3,16); a3 += __shfl_xor(a3,32);
    a4 += __shfl_xor(a4,16); a4 += __shfl_xor(a4,32);
    a5 += __shfl_xor(a5,16); a5 += __shfl_xor(a5,32);
    a6 += __shfl_xor(a6,16); a6 += __shfl_xor(a6,32);
    a7 += __shfl_xor(a7,16); a7 += __shfl_xor(a7,32);
    if (sub==0){
      float4 o0; o0.x=a0; o0.y=a1; o0.z=a2; o0.w=a3;
      float4 o1; o1.x=a4; o1.y=a5; o1.z=a6; o1.w=a7;
      *(float4*)&a_s[(wv*4+r)*128 + k*8] = o0;
      *(float4*)&a_s[(wv*4+r)*128 + k*8 + 4] = o1;
    }
  }
  __syncthreads();

  // ---- GEMM phase: thread owns 2 cols x 4 rows (same rows its wave produced)
  int jj = lane*2;
  float b0 = bl[jj], b1 = bl[jj+1];
  float acc[4][2];
  #pragma unroll
  for (int r=0;r<4;r++){ acc[r][0]=b0; acc[r][1]=b1; }
  #pragma unroll 4
  for (int kk=0;kk<128;kk++){
    float2 w2 = *(const float2*)&wTl[kk*128 + jj];
    #pragma unroll
    for (int r=0;r<4;r++){
      float a = a_s[(wv*4+r)*128 + kk];
      acc[r][0] = fmaf(a, w2.x, acc[r][0]);
      acc[r][1] = fmaf(a, w2.y, acc[r][1]);
    }
  }
  float zc0 = 0.f, zc1 = 0.f;
  #pragma unroll
  for (int r=0;r<4;r++){
    int row = i0 + wv*4 + r;
    float e0 = acc[r][0] > 0.f ? acc[r][0] : expm1f(acc[r][0]);
    float e1 = acc[r][1] > 0.f ? acc[r][1] : expm1f(acc[r][1]);
    zc0 += e0; zc1 += e1;
    if (!last)
      hout[(size_t)row*64 + (jj>>1)] = pack_bf2(e0, e1);
  }
  atomicAdd(&zp[jj], zc0); atomicAdd(&zp[jj+1], zc1);
  __syncthreads();
  if (t < 128) atomicAdd(&z[((blockIdx.x&15)<<7) + t], zp[t]);
}

// hz = leaky_relu(fc1_W @ zbar + fc1_b); zbar from 16 partial column-sum slots
__global__ __launch_bounds__(128) void k_hz(const float* __restrict__ z, const float* __restrict__ fc1W,
                     const float* __restrict__ fc1b, float* __restrict__ hz){
  __shared__ float zs[128];
  int j = threadIdx.x;
  float s = 0.f;
  #pragma unroll
  for (int q=0;q<16;q++) s += z[(q<<7) + j];
  zs[j] = s * (1.0f / (4.0f * (float)NN));
  __syncthreads();
  float acc = fc1b[j];
  const float* wr = &fc1W[j*128];
  #pragma unroll 8
  for (int k=0;k<128;k++)
    acc = fmaf(zs[k], wr[k], acc);
  hz[j] = acc >= 0.f ? acc : 0.2f*acc;
}

__global__ __launch_bounds__(256) void k_wcol(const float* __restrict__ hz, const float* __restrict__ W,
                       const float* __restrict__ b, float* __restrict__ wcol){
  __shared__ float hzs[128];
  int t = threadIdx.x;
  if (t < 128) hzs[t] = hz[t];
  __syncthreads();
  int m = blockIdx.x*256 + t; // < 2048
  float acc = b[m];
  const float* wr = &W[(size_t)m*128];
  #pragma unroll 8
  for (int k=0;k<128;k++)
    acc = fmaf(hzs[k], wr[k], acc);
  wcol[m] = acc;
}

// ---------------- big GEMV: wrow[m] = fcrow_W[m,:] . hz + b[m] ----------------
__global__ __launch_bounds__(256) void k_wrow(const float* __restrict__ hz, const float* __restrict__ W,
                       const float* __restrict__ b, float* __restrict__ wrow){
  int lane = threadIdx.x & 63;
  int sub = lane >> 5, k = lane & 31;
  float4 hk = *(const float4*)&hz[k*4];
  int wid = (blockIdx.x*blockDim.x + threadIdx.x) >> 6;
  int nw = (gridDim.x*blockDim.x) >> 6;
  const int NITER = NN*RR/2; // 400000
  for (int it = wid; it < NITER; it += nw){
    int row = it*2 + sub;
    float4 wv = *(const float4*)&W[(size_t)row*128 + k*4];
    float acc = wv.x*hk.x;
    acc = fmaf(wv.y, hk.y, acc);
    acc = fmaf(wv.z, hk.z, acc);
    acc = fmaf(wv.w, hk.w, acc);
    acc += __shfl_xor(acc,1); acc += __shfl_xor(acc,2);
    acc += __shfl_xor(acc,4); acc += __shfl_xor(acc,8);
    acc += __shfl_xor(acc,16);
    if (k==0) wrow[row] = acc + b[row];
  }
}

// ---------------- final: out = ini * (1 + W_row @ W_col) ----------------
__global__ __launch_bounds__(256) void k_final(const float* __restrict__ ini, const float* __restrict__ wrow,
                        const float* __restrict__ wcol, float* __restrict__ out){
  __shared__ float wc[16*128];
  int t = threadIdx.x;
  ((float4*)wc)[t] = ((const float4*)wcol)[t];
  ((float4*)wc)[t+256] = ((const float4*)wcol)[t+256];
  __syncthreads();
  int gid = blockIdx.x*256 + t; // N*32 = 1.6M
  int i = gid >> 5, k = gid & 31;
  float4 a; a.x=0.f; a.y=0.f; a.z=0.f; a.w=0.f;
  const float* wri = &wrow[(size_t)i*16];
  #pragma unroll
  for (int r=0;r<16;r++){
    float w = wri[r];
    const float4 c = *(const float4*)&wc[r*128 + k*4];
    a.x = fmaf(w, c.x, a.x); a.y = fmaf(w, c.y, a.y);
    a.z = fmaf(w, c.z, a.z); a.w = fmaf(w, c.w, a.w);
  }
  float4 e = *(const float4*)&ini[(size_t)i*128 + k*4];
  float4 o;
  o.x = e.x*(1.f+a.x); o.y = e.y*(1.f+a.y);
  o.z = e.z*(1.f+a.z); o.w = e.w*(1.f+a.w);
  *(float4*)&out[(size_t)i*128 + k*4] = o;
}

extern "C" void kernel_launch(void* const* d_in, const int* in_sizes, int n_in,
                              void* d_out, int out_size, void* d_ws, size_t ws_size,
                              hipStream_t stream) {
  const int* adj_rows = (const int*)d_in[0];
  const int* adj_cols = (const int*)d_in[1];
  const float* adj_vals = (const float*)d_in[2];
  const float* node_feats = (const float*)d_in[3];
  const float* gnn_W = (const float*)d_in[4];
  const float* gnn_b = (const float*)d_in[5];
  const float* fc1_W = (const float*)d_in[6];
  const float* fc1_b = (const float*)d_in[7];
  const float* fcrow_W = (const float*)d_in[8];
  const float* fcrow_b = (const float*)d_in[9];
  const float* fccol_W = (const float*)d_in[10];
  const float* fccol_b = (const float*)d_in[11];
  const float* ini = (const float*)d_in[12];
  float* out = (float*)d_out;

  char* w = (char*)d_ws;
  auto alloc = [&](size_t bytes)->void*{ void* p = (void*)w; w += (bytes + 255) & ~(size_t)255; return p; };
  u32*   hbf_a  = (u32*)  alloc((size_t)NN*DD*2);   // h as packed bf16 (ping)
  u32*   hbf_b  = (u32*)  alloc((size_t)NN*DD*2);   // h as packed bf16 (pong)
  int2*  colval = (int2*) alloc((size_t)EE*8);
  int*   cnt    = (int*)  alloc((size_t)NN*4);
  int*   row_ptr= (int*)  alloc((size_t)NN*4);
  int*   cursor = (int*)  alloc((size_t)NN*4);
  int*   bsum   = (int*)  alloc(256*4);
  float* wT     = (float*)alloc(3*128*128*4);
  float* zb     = (float*)alloc(16*128*4);          // 16 partial column-sum slots
  float* hzb    = (float*)alloc(128*4);
  float* wcolb  = (float*)alloc(2048*4);
  float* wrowb  = (float*)alloc((size_t)NN*RR*4);

  hipMemsetAsync(cnt, 0, NN*4, stream);
  hipMemsetAsync(zb, 0, 16*128*4, stream);

  k_hist<<<EE/256, 256, 0, stream>>>(adj_rows, cnt);
  k_scanA<<<256, 256, 0, stream>>>(cnt, bsum);
  k_scanB<<<1, 256, 0, stream>>>(bsum);
  k_scanC<<<256, 256, 0, stream>>>(cnt, bsum, row_ptr, cursor);
  k_scatter<<<EE/256, 256, 0, stream>>>(adj_rows, adj_cols, adj_vals, cursor, colval);
  k_init<<<400, 256, 0, stream>>>((const float4*)node_feats, (uint2*)hbf_a, zb);
  k_wT<<<3*128*128/256, 256, 0, stream>>>(gnn_W, wT);

  const u32* hin = hbf_a; u32* hout = hbf_b;
  for (int l=0; l<LLAYERS; ++l){
    k_layer<<<NN/16, 256, 0, stream>>>(row_ptr, cnt, colval, hin, wT + l*16384,
                                       gnn_b + l*128, hout, zb, (l==LLAYERS-1) ? 1 : 0);
    const u32* tmp = hin; hin = hout; hout = (u32*)tmp;
  }

  k_hz<<<1, 128, 0, stream>>>(zb, fc1_W, fc1_b, hzb);
  k_wcol<<<8, 256, 0, stream>>>(hzb, fccol_W, fccol_b, wcolb);
  k_wrow<<<2048, 256, 0, stream>>>(hzb, fcrow_W, fcrow_b, wrowb);
  k_final<<<NN*32/256, 256, 0, stream>>>(ini, wrowb, wcolb, out);
}

// Round 2
// 1093.510 us; speedup vs baseline: 1.2004x; 1.0161x over previous
//
#include <hip/hip_runtime.h>
#include <hip/hip_bf16.h>
#include <math.h>

#define NN 50000
#define DD 128
#define LLAYERS 3
#define RR 16
#define EE 1600000

typedef unsigned int u32;

__device__ __forceinline__ float bflo(u32 u){ union{u32 i;float f;}a; a.i=u<<16; return a.f; }
__device__ __forceinline__ float bfhi(u32 u){ union{u32 i;float f;}a; a.i=u&0xffff0000u; return a.f; }
__device__ __forceinline__ u32 pack_bf2(float x, float y){
  union{float f;u32 i;}a,b; a.f=x; b.f=y;
  u32 xr = (a.i + 0x7fffu + ((a.i>>16)&1u)) >> 16;
  u32 yr = (b.i + 0x7fffu + ((b.i>>16)&1u)) & 0xffff0000u;
  return (xr & 0xffffu) | yr;
}

// ---------------- CSR build (rows padded to multiple of 8 edges) ----------------
__global__ __launch_bounds__(256) void k_hist(const int* __restrict__ rows, int* __restrict__ cnt){
  int e = blockIdx.x*256 + threadIdx.x;
  if (e < EE) atomicAdd(&cnt[rows[e]], 1);
}

__global__ __launch_bounds__(256) void k_scanA(const int* __restrict__ cnt, int* __restrict__ bsum){
  __shared__ int s[256];
  int i = blockIdx.x*256 + threadIdx.x;
  int v = (i < NN) ? ((cnt[i]+7)&~7) : 0;   // padded counts
  s[threadIdx.x] = v; __syncthreads();
  for (int off=128; off>0; off>>=1){
    if (threadIdx.x < off) s[threadIdx.x] += s[threadIdx.x+off];
    __syncthreads();
  }
  if (threadIdx.x==0) bsum[blockIdx.x] = s[0];
}

__global__ __launch_bounds__(256) void k_scanB(int* bsum){
  __shared__ int s[256];
  int t = threadIdx.x;
  int v = bsum[t];
  s[t] = v; __syncthreads();
  for (int off=1; off<256; off<<=1){
    int x = (t>=off) ? s[t-off] : 0; __syncthreads();
    s[t] += x; __syncthreads();
  }
  bsum[t] = s[t] - v; // exclusive block offsets
}

__global__ __launch_bounds__(256) void k_scanC(const int* __restrict__ cnt, const int* __restrict__ bsum,
                        int* __restrict__ row_ptr, int* __restrict__ cursor){
  __shared__ int s[256];
  int t = threadIdx.x; int i = blockIdx.x*256 + t;
  int v = (i<NN)?((cnt[i]+7)&~7):0;         // padded counts
  s[t]=v; __syncthreads();
  for (int off=1; off<256; off<<=1){
    int x=(t>=off)?s[t-off]:0; __syncthreads();
    s[t]+=x; __syncthreads();
  }
  if (i<NN){ int e = bsum[blockIdx.x] + s[t]-v; row_ptr[i]=e; cursor[i]=e; }
}

// fill pad slots [row_ptr+cnt, row_ptr+pad(cnt)) with (col=0,val=0); tail-pad 128 after last row
__global__ __launch_bounds__(256) void k_pad(const int* __restrict__ row_ptr, const int* __restrict__ cnt,
                                             int2* __restrict__ colval){
  int i = blockIdx.x*256 + threadIdx.x;
  if (i < NN){
    int b = row_ptr[i], n = cnt[i], np = (n+7)&~7;
    int2 z0; z0.x = 0; z0.y = 0;
    for (int p=b+n; p<b+np; ++p) colval[p] = z0;
    if (i == NN-1){
      for (int p=b+np; p<b+np+128; ++p) colval[p] = z0;
    }
  }
}

// pack (col, val) into one 8B scattered store
__global__ __launch_bounds__(256) void k_scatter(const int* __restrict__ rows, const int* __restrict__ cols,
                          const float* __restrict__ vals,
                          int* __restrict__ cursor, int2* __restrict__ colval){
  int e = blockIdx.x*256+threadIdx.x;
  if (e<EE){
    int r = rows[e];
    int p = atomicAdd(&cursor[r],1);
    int2 cv; cv.x = cols[e]; cv.y = __float_as_int(vals[e]);
    colval[p] = cv;
  }
}

// ---------------- init: h -> bf16 packed, accumulate z column sums (16 partial slots) ----------------
__global__ __launch_bounds__(256) void k_init(const float4* __restrict__ nf, uint2* __restrict__ hbf,
                                              float* __restrict__ z){
  __shared__ float zp[128];
  int t = threadIdx.x;
  if (t < 128) zp[t] = 0.f;
  float a0=0.f,a1=0.f,a2=0.f,a3=0.f;
  for (int i = blockIdx.x*256 + t; i < NN*DD/4; i += gridDim.x*256){
    float4 v = nf[i];
    uint2 p; p.x = pack_bf2(v.x, v.y); p.y = pack_bf2(v.z, v.w);
    hbf[i] = p;
    a0 += v.x; a1 += v.y; a2 += v.z; a3 += v.w;
  }
  __syncthreads();
  int c = (t*4) & 127;
  atomicAdd(&zp[c],a0); atomicAdd(&zp[c+1],a1); atomicAdd(&zp[c+2],a2); atomicAdd(&zp[c+3],a3);
  __syncthreads();
  if (t < 128) atomicAdd(&z[((blockIdx.x&15)<<7) + t], zp[t]);
}

// transpose gnn_W (L x D x D, row-major [l][j][k]) -> wT [l][k][j]
__global__ __launch_bounds__(256) void k_wT(const float* __restrict__ W, float* __restrict__ wT){
  int idx = blockIdx.x*256+threadIdx.x; // 49152
  int l = idx >> 14; int r = idx & 16383; int k = r >> 7; int j = r & 127;
  wT[(l<<14) + k*128 + j] = W[(l<<14) + j*128 + k];
}

#define FMA8(v, h)                                         \
  a0 = fmaf(v, bflo(h.x), a0); a1 = fmaf(v, bfhi(h.x), a1);\
  a2 = fmaf(v, bflo(h.y), a2); a3 = fmaf(v, bfhi(h.y), a3);\
  a4 = fmaf(v, bflo(h.z), a4); a5 = fmaf(v, bfhi(h.z), a5);\
  a6 = fmaf(v, bflo(h.w), a6); a7 = fmaf(v, bfhi(h.w), a7);

// ---------------- fused layer: SPMM (16-row tile -> LDS) + GEMM + ELU + z colsum + bf16 out ----------
// SPMM: software-pipelined 2 stages deep (cv at t+2, gathers at t+1, FMA at t); rows pre-padded
// to a multiple of 8 edges with val=0 entries -> uniform trip count, no tail, safe over-reads.
__global__ __launch_bounds__(256) void k_layer(const int* __restrict__ row_ptr, const int* __restrict__ cnt,
                       const int2* __restrict__ colval,
                       const u32* __restrict__ hin, const float* __restrict__ wTl,
                       const float* __restrict__ bl,
                       u32* __restrict__ hout, float* __restrict__ z, int last){
  __shared__ float a_s[16*128];
  __shared__ float zp[128];
  int t = threadIdx.x;
  if (t < 128) zp[t] = 0.f;
  int i0 = blockIdx.x * 16;
  int lane = t & 63;
  int wv = t >> 6;                    // wave id 0..3
  int sub = lane >> 4, k = lane & 15; // quarter-wave: 16 lanes x 16B = one 128-feat bf16 row

  for (int r = 0; r < 4; ++r){
    int row = i0 + wv*4 + r;
    int base = row_ptr[row], n = cnt[row];
    int iters = (n + 7) >> 3;
    const int2* cvp = colval + base + sub;
    float a0=0,a1=0,a2=0,a3=0,a4=0,a5=0,a6=0,a7=0;

    // prologue: cv for t=0,1; gathers for t=0
    int2 c0a = cvp[0],  c0b = cvp[4];
    int2 c1a = cvp[8],  c1b = cvp[12];
    uint4 h0a = *(const uint4*)&hin[((size_t)(u32)c0a.x<<6) + (k<<2)];
    uint4 h0b = *(const uint4*)&hin[((size_t)(u32)c0b.x<<6) + (k<<2)];

    for (int it = 0; it < iters; ++it){
      int2 c2a = cvp[16], c2b = cvp[20];                                  // cv for t+2
      uint4 h1a = *(const uint4*)&hin[((size_t)(u32)c1a.x<<6) + (k<<2)];  // gathers for t+1
      uint4 h1b = *(const uint4*)&hin[((size_t)(u32)c1b.x<<6) + (k<<2)];
      float v0 = __int_as_float(c0a.y);
      float v1 = __int_as_float(c0b.y);
      FMA8(v0, h0a);
      FMA8(v1, h0b);
      c0a = c1a; c0b = c1b; c1a = c2a; c1b = c2b;
      h0a = h1a; h0b = h1b;
      cvp += 8;
    }

    a0 += __shfl_xor(a0,16); a0 += __shfl_xor(a0,32);
    a1 += __shfl_xor(a1,16); a1 += __shfl_xor(a1,32);
    a2 += __shfl_xor(a2,16); a2 += __shfl_xor(a2,32);
    a3 += __shfl_xor(a3,16); a3 += __shfl_xor(a3,32);
    a4 += __shfl_xor(a4,16); a4 += __shfl_xor(a4,32);
    a5 += __shfl_xor(a5,16); a5 += __shfl_xor(a5,32);
    a6 += __shfl_xor(a6,16); a6 += __shfl_xor(a6,32);
    a7 += __shfl_xor(a7,16); a7 += __shfl_xor(a7,32);
    if (sub==0){
      float4 o0; o0.x=a0; o0.y=a1; o0.z=a2; o0.w=a3;
      float4 o1; o1.x=a4; o1.y=a5; o1.z=a6; o1.w=a7;
      *(float4*)&a_s[(wv*4+r)*128 + k*8] = o0;
      *(float4*)&a_s[(wv*4+r)*128 + k*8 + 4] = o1;
    }
  }
  __syncthreads();

  // ---- GEMM phase: thread owns 2 cols x 4 rows (same rows its wave produced)
  int jj = lane*2;
  float b0 = bl[jj], b1 = bl[jj+1];
  float acc[4][2];
  #pragma unroll
  for (int r=0;r<4;r++){ acc[r][0]=b0; acc[r][1]=b1; }
  #pragma unroll 4
  for (int kk=0;kk<128;kk++){
    float2 w2 = *(const float2*)&wTl[kk*128 + jj];
    #pragma unroll
    for (int r=0;r<4;r++){
      float a = a_s[(wv*4+r)*128 + kk];
      acc[r][0] = fmaf(a, w2.x, acc[r][0]);
      acc[r][1] = fmaf(a, w2.y, acc[r][1]);
    }
  }
  float zc0 = 0.f, zc1 = 0.f;
  #pragma unroll
  for (int r=0;r<4;r++){
    int row = i0 + wv*4 + r;
    float e0 = acc[r][0] > 0.f ? acc[r][0] : expm1f(acc[r][0]);
    float e1 = acc[r][1] > 0.f ? acc[r][1] : expm1f(acc[r][1]);
    zc0 += e0; zc1 += e1;
    if (!last)
      hout[(size_t)row*64 + (jj>>1)] = pack_bf2(e0, e1);
  }
  atomicAdd(&zp[jj], zc0); atomicAdd(&zp[jj+1], zc1);
  __syncthreads();
  if (t < 128) atomicAdd(&z[((blockIdx.x&15)<<7) + t], zp[t]);
}

// hz = leaky_relu(fc1_W @ zbar + fc1_b); zbar from 16 partial column-sum slots
__global__ __launch_bounds__(128) void k_hz(const float* __restrict__ z, const float* __restrict__ fc1W,
                     const float* __restrict__ fc1b, float* __restrict__ hz){
  __shared__ float zs[128];
  int j = threadIdx.x;
  float s = 0.f;
  #pragma unroll
  for (int q=0;q<16;q++) s += z[(q<<7) + j];
  zs[j] = s * (1.0f / (4.0f * (float)NN));
  __syncthreads();
  float acc = fc1b[j];
  const float* wr = &fc1W[j*128];
  #pragma unroll 8
  for (int k=0;k<128;k++)
    acc = fmaf(zs[k], wr[k], acc);
  hz[j] = acc >= 0.f ? acc : 0.2f*acc;
}

__global__ __launch_bounds__(256) void k_wcol(const float* __restrict__ hz, const float* __restrict__ W,
                       const float* __restrict__ b, float* __restrict__ wcol){
  __shared__ float hzs[128];
  int t = threadIdx.x;
  if (t < 128) hzs[t] = hz[t];
  __syncthreads();
  int m = blockIdx.x*256 + t; // < 2048
  float acc = b[m];
  const float* wr = &W[(size_t)m*128];
  #pragma unroll 8
  for (int k=0;k<128;k++)
    acc = fmaf(hzs[k], wr[k], acc);
  wcol[m] = acc;
}

// ---------------- big GEMV: wrow[m] = fcrow_W[m,:] . hz + b[m] ----------------
__global__ __launch_bounds__(256) void k_wrow(const float* __restrict__ hz, const float* __restrict__ W,
                       const float* __restrict__ b, float* __restrict__ wrow){
  int lane = threadIdx.x & 63;
  int sub = lane >> 5, k = lane & 31;
  float4 hk = *(const float4*)&hz[k*4];
  int wid = (blockIdx.x*blockDim.x + threadIdx.x) >> 6;
  int nw = (gridDim.x*blockDim.x) >> 6;
  const int NITER = NN*RR/2; // 400000
  for (int it = wid; it < NITER; it += nw){
    int row = it*2 + sub;
    float4 wv = *(const float4*)&W[(size_t)row*128 + k*4];
    float acc = wv.x*hk.x;
    acc = fmaf(wv.y, hk.y, acc);
    acc = fmaf(wv.z, hk.z, acc);
    acc = fmaf(wv.w, hk.w, acc);
    acc += __shfl_xor(acc,1); acc += __shfl_xor(acc,2);
    acc += __shfl_xor(acc,4); acc += __shfl_xor(acc,8);
    acc += __shfl_xor(acc,16);
    if (k==0) wrow[row] = acc + b[row];
  }
}

// ---------------- final: out = ini * (1 + W_row @ W_col) ----------------
__global__ __launch_bounds__(256) void k_final(const float* __restrict__ ini, const float* __restrict__ wrow,
                        const float* __restrict__ wcol, float* __restrict__ out){
  __shared__ float wc[16*128];
  int t = threadIdx.x;
  ((float4*)wc)[t] = ((const float4*)wcol)[t];
  ((float4*)wc)[t+256] = ((const float4*)wcol)[t+256];
  __syncthreads();
  int gid = blockIdx.x*256 + t; // N*32 = 1.6M
  int i = gid >> 5, k = gid & 31;
  float4 a; a.x=0.f; a.y=0.f; a.z=0.f; a.w=0.f;
  const float* wri = &wrow[(size_t)i*16];
  #pragma unroll
  for (int r=0;r<16;r++){
    float w = wri[r];
    const float4 c = *(const float4*)&wc[r*128 + k*4];
    a.x = fmaf(w, c.x, a.x); a.y = fmaf(w, c.y, a.y);
    a.z = fmaf(w, c.z, a.z); a.w = fmaf(w, c.w, a.w);
  }
  float4 e = *(const float4*)&ini[(size_t)i*128 + k*4];
  float4 o;
  o.x = e.x*(1.f+a.x); o.y = e.y*(1.f+a.y);
  o.z = e.z*(1.f+a.z); o.w = e.w*(1.f+a.w);
  *(float4*)&out[(size_t)i*128 + k*4] = o;
}

extern "C" void kernel_launch(void* const* d_in, const int* in_sizes, int n_in,
                              void* d_out, int out_size, void* d_ws, size_t ws_size,
                              hipStream_t stream) {
  const int* adj_rows = (const int*)d_in[0];
  const int* adj_cols = (const int*)d_in[1];
  const float* adj_vals = (const float*)d_in[2];
  const float* node_feats = (const float*)d_in[3];
  const float* gnn_W = (const float*)d_in[4];
  const float* gnn_b = (const float*)d_in[5];
  const float* fc1_W = (const float*)d_in[6];
  const float* fc1_b = (const float*)d_in[7];
  const float* fcrow_W = (const float*)d_in[8];
  const float* fcrow_b = (const float*)d_in[9];
  const float* fccol_W = (const float*)d_in[10];
  const float* fccol_b = (const float*)d_in[11];
  const float* ini = (const float*)d_in[12];
  float* out = (float*)d_out;

  char* w = (char*)d_ws;
  auto alloc = [&](size_t bytes)->void*{ void* p = (void*)w; w += (bytes + 255) & ~(size_t)255; return p; };
  u32*   hbf_a  = (u32*)  alloc((size_t)NN*DD*2);   // h as packed bf16 (ping)
  u32*   hbf_b  = (u32*)  alloc((size_t)NN*DD*2);   // h as packed bf16 (pong)
  int2*  colval = (int2*) alloc(((size_t)EE + 8*NN + 256)*8);  // padded CSR
  int*   cnt    = (int*)  alloc((size_t)NN*4);
  int*   row_ptr= (int*)  alloc((size_t)NN*4);
  int*   cursor = (int*)  alloc((size_t)NN*4);
  int*   bsum   = (int*)  alloc(256*4);
  float* wT     = (float*)alloc(3*128*128*4);
  float* zb     = (float*)alloc(16*128*4);          // 16 partial column-sum slots
  float* hzb    = (float*)alloc(128*4);
  float* wcolb  = (float*)alloc(2048*4);
  float* wrowb  = (float*)alloc((size_t)NN*RR*4);

  hipMemsetAsync(cnt, 0, NN*4, stream);
  hipMemsetAsync(zb, 0, 16*128*4, stream);

  k_hist<<<EE/256, 256, 0, stream>>>(adj_rows, cnt);
  k_scanA<<<256, 256, 0, stream>>>(cnt, bsum);
  k_scanB<<<1, 256, 0, stream>>>(bsum);
  k_scanC<<<256, 256, 0, stream>>>(cnt, bsum, row_ptr, cursor);
  k_pad<<<(NN+255)/256, 256, 0, stream>>>(row_ptr, cnt, colval);
  k_scatter<<<EE/256, 256, 0, stream>>>(adj_rows, adj_cols, adj_vals, cursor, colval);
  k_init<<<400, 256, 0, stream>>>((const float4*)node_feats, (uint2*)hbf_a, zb);
  k_wT<<<3*128*128/256, 256, 0, stream>>>(gnn_W, wT);

  const u32* hin = hbf_a; u32* hout = hbf_b;
  for (int l=0; l<LLAYERS; ++l){
    k_layer<<<NN/16, 256, 0, stream>>>(row_ptr, cnt, colval, hin, wT + l*16384,
                                       gnn_b + l*128, hout, zb, (l==LLAYERS-1) ? 1 : 0);
    const u32* tmp = hin; hin = hout; hout = (u32*)tmp;
  }

  k_hz<<<1, 128, 0, stream>>>(zb, fc1_W, fc1_b, hzb);
  k_wcol<<<8, 256, 0, stream>>>(hzb, fccol_W, fccol_b, wcolb);
  k_wrow<<<2048, 256, 0, stream>>>(hzb, fcrow_W, fcrow_b, wrowb);
  k_final<<<NN*32/256, 256, 0, stream>>>(ini, wrowb, wcolb, out);
}

// Round 4
// 1033.326 us; speedup vs baseline: 1.2703x; 1.0582x over previous
//
#include <hip/hip_runtime.h>
#include <hip/hip_bf16.h>
#include <math.h>

#define NN 50000
#define DD 128
#define LLAYERS 3
#define RR 16
#define EE 1600000

typedef unsigned int u32;

__device__ __forceinline__ float bflo(u32 u){ union{u32 i;float f;}a; a.i=u<<16; return a.f; }
__device__ __forceinline__ float bfhi(u32 u){ union{u32 i;float f;}a; a.i=u&0xffff0000u; return a.f; }
__device__ __forceinline__ u32 pack_bf2(float x, float y){
  union{float f;u32 i;}a,b; a.f=x; b.f=y;
  u32 xr = (a.i + 0x7fffu + ((a.i>>16)&1u)) >> 16;
  u32 yr = (b.i + 0x7fffu + ((b.i>>16)&1u)) & 0xffff0000u;
  return (xr & 0xffffu) | yr;
}

// ---------------- CSR build (rows padded to multiple of 8 edges) ----------------
__global__ __launch_bounds__(256) void k_hist(const int* __restrict__ rows, int* __restrict__ cnt){
  int e = blockIdx.x*256 + threadIdx.x;
  if (e < EE) atomicAdd(&cnt[rows[e]], 1);
}

__global__ __launch_bounds__(256) void k_scanA(const int* __restrict__ cnt, int* __restrict__ bsum){
  __shared__ int s[256];
  int i = blockIdx.x*256 + threadIdx.x;
  int v = (i < NN) ? ((cnt[i]+7)&~7) : 0;   // padded counts
  s[threadIdx.x] = v; __syncthreads();
  for (int off=128; off>0; off>>=1){
    if (threadIdx.x < off) s[threadIdx.x] += s[threadIdx.x+off];
    __syncthreads();
  }
  if (threadIdx.x==0) bsum[blockIdx.x] = s[0];
}

__global__ __launch_bounds__(256) void k_scanB(int* bsum){
  __shared__ int s[256];
  int t = threadIdx.x;
  int v = bsum[t];
  s[t] = v; __syncthreads();
  for (int off=1; off<256; off<<=1){
    int x = (t>=off) ? s[t-off] : 0; __syncthreads();
    s[t] += x; __syncthreads();
  }
  bsum[t] = s[t] - v; // exclusive block offsets
}

// scanC + pad-fill fused: computes row_ptr/cursor AND zeroes the pad slots
__global__ __launch_bounds__(256) void k_scanC(const int* __restrict__ cnt, const int* __restrict__ bsum,
                        int* __restrict__ row_ptr, int* __restrict__ cursor,
                        int2* __restrict__ colval){
  __shared__ int s[256];
  int t = threadIdx.x; int i = blockIdx.x*256 + t;
  int n = (i<NN)?cnt[i]:0;
  int v = (n+7)&~7;                          // padded count
  s[t]=v; __syncthreads();
  for (int off=1; off<256; off<<=1){
    int x=(t>=off)?s[t-off]:0; __syncthreads();
    s[t]+=x; __syncthreads();
  }
  if (i<NN){
    int e = bsum[blockIdx.x] + s[t]-v;
    row_ptr[i]=e; cursor[i]=e;
    int2 z0; z0.x=0; z0.y=0;
    for (int p=e+n; p<e+v; ++p) colval[p] = z0;     // pad this row
    if (i == NN-1){                                  // tail pad for pipeline over-read
      for (int p=e+v; p<e+v+128; ++p) colval[p] = z0;
    }
  }
}

// pack (col, val) into one 8B scattered store
__global__ __launch_bounds__(256) void k_scatter(const int* __restrict__ rows, const int* __restrict__ cols,
                          const float* __restrict__ vals,
                          int* __restrict__ cursor, int2* __restrict__ colval){
  int e = blockIdx.x*256+threadIdx.x;
  if (e<EE){
    int r = rows[e];
    int p = atomicAdd(&cursor[r],1);
    int2 cv; cv.x = cols[e]; cv.y = __float_as_int(vals[e]);
    colval[p] = cv;
  }
}

// ---------------- init: h -> bf16 packed + z column sums + gnn_W transpose ----------------
__global__ __launch_bounds__(256) void k_initwT(const float4* __restrict__ nf, uint2* __restrict__ hbf,
                                                float* __restrict__ z,
                                                const float* __restrict__ W, float* __restrict__ wT){
  __shared__ float zp[128];
  int t = threadIdx.x;
  if (t < 128) zp[t] = 0.f;
  // fold gnn_W transpose into the first 192 blocks (one elem per thread)
  if (blockIdx.x < 192){
    int idx = blockIdx.x*256+t; // 49152
    int l = idx >> 14; int r = idx & 16383; int k = r >> 7; int j = r & 127;
    wT[(l<<14) + k*128 + j] = W[(l<<14) + j*128 + k];
  }
  float a0=0.f,a1=0.f,a2=0.f,a3=0.f;
  for (int i = blockIdx.x*256 + t; i < NN*DD/4; i += gridDim.x*256){
    float4 v = nf[i];
    uint2 p; p.x = pack_bf2(v.x, v.y); p.y = pack_bf2(v.z, v.w);
    hbf[i] = p;
    a0 += v.x; a1 += v.y; a2 += v.z; a3 += v.w;
  }
  __syncthreads();
  int c = (t*4) & 127;
  atomicAdd(&zp[c],a0); atomicAdd(&zp[c+1],a1); atomicAdd(&zp[c+2],a2); atomicAdd(&zp[c+3],a3);
  __syncthreads();
  if (t < 128) atomicAdd(&z[((blockIdx.x&15)<<7) + t], zp[t]);
}

#define FMA8(v, h)                                         \
  a0 = fmaf(v, bflo(h.x), a0); a1 = fmaf(v, bfhi(h.x), a1);\
  a2 = fmaf(v, bflo(h.y), a2); a3 = fmaf(v, bfhi(h.y), a3);\
  a4 = fmaf(v, bflo(h.z), a4); a5 = fmaf(v, bfhi(h.z), a5);\
  a6 = fmaf(v, bflo(h.w), a6); a7 = fmaf(v, bfhi(h.w), a7);

// ---------------- fused layer: SPMM (16-row tile -> LDS) + GEMM + ELU + z colsum + bf16 out ----------
// GEMM reads wT via LDS staging (4 x 16KB chunks) instead of 128 global float2 loads/thread,
// removing VMEM-issue contention with co-resident blocks' SPMM gathers.
__global__ __launch_bounds__(256) void k_layer(const int* __restrict__ row_ptr, const int* __restrict__ cnt,
                       const int2* __restrict__ colval,
                       const u32* __restrict__ hin, const float* __restrict__ wTl,
                       const float* __restrict__ bl,
                       u32* __restrict__ hout, float* __restrict__ z, int last){
  __shared__ float a_s[16*128];   // 8 KB
  __shared__ float w_s[32*128];   // 16 KB staging for one wT chunk
  __shared__ float zp[128];
  int t = threadIdx.x;
  if (t < 128) zp[t] = 0.f;
  int i0 = blockIdx.x * 16;
  int lane = t & 63;
  int wv = t >> 6;                    // wave id 0..3
  int sub = lane >> 4, k = lane & 15; // quarter-wave: 16 lanes x 16B = one 128-feat bf16 row

  for (int r = 0; r < 4; ++r){
    int row = i0 + wv*4 + r;
    int base = row_ptr[row], n = cnt[row];
    int iters = (n + 7) >> 3;
    const int2* cvp = colval + base + sub;
    float a0=0,a1=0,a2=0,a3=0,a4=0,a5=0,a6=0,a7=0;

    // prologue: cv for t=0,1; gathers for t=0
    int2 c0a = cvp[0],  c0b = cvp[4];
    int2 c1a = cvp[8],  c1b = cvp[12];
    uint4 h0a = *(const uint4*)&hin[((size_t)(u32)c0a.x<<6) + (k<<2)];
    uint4 h0b = *(const uint4*)&hin[((size_t)(u32)c0b.x<<6) + (k<<2)];

    for (int it = 0; it < iters; ++it){
      int2 c2a = cvp[16], c2b = cvp[20];                                  // cv for t+2
      uint4 h1a = *(const uint4*)&hin[((size_t)(u32)c1a.x<<6) + (k<<2)];  // gathers for t+1
      uint4 h1b = *(const uint4*)&hin[((size_t)(u32)c1b.x<<6) + (k<<2)];
      float v0 = __int_as_float(c0a.y);
      float v1 = __int_as_float(c0b.y);
      FMA8(v0, h0a);
      FMA8(v1, h0b);
      c0a = c1a; c0b = c1b; c1a = c2a; c1b = c2b;
      h0a = h1a; h0b = h1b;
      cvp += 8;
    }

    a0 += __shfl_xor(a0,16); a0 += __shfl_xor(a0,32);
    a1 += __shfl_xor(a1,16); a1 += __shfl_xor(a1,32);
    a2 += __shfl_xor(a2,16); a2 += __shfl_xor(a2,32);
    a3 += __shfl_xor(a3,16); a3 += __shfl_xor(a3,32);
    a4 += __shfl_xor(a4,16); a4 += __shfl_xor(a4,32);
    a5 += __shfl_xor(a5,16); a5 += __shfl_xor(a5,32);
    a6 += __shfl_xor(a6,16); a6 += __shfl_xor(a6,32);
    a7 += __shfl_xor(a7,16); a7 += __shfl_xor(a7,32);
    if (sub==0){
      float4 o0; o0.x=a0; o0.y=a1; o0.z=a2; o0.w=a3;
      float4 o1; o1.x=a4; o1.y=a5; o1.z=a6; o1.w=a7;
      *(float4*)&a_s[(wv*4+r)*128 + k*8] = o0;
      *(float4*)&a_s[(wv*4+r)*128 + k*8 + 4] = o1;
    }
  }
  __syncthreads();

  // ---- GEMM phase: thread owns 2 cols x 4 rows; wT staged through LDS in 4 chunks of 32 k
  int jj = lane*2;
  float b0 = bl[jj], b1 = bl[jj+1];
  float acc[4][2];
  #pragma unroll
  for (int r=0;r<4;r++){ acc[r][0]=b0; acc[r][1]=b1; }
  for (int ch=0; ch<4; ++ch){
    const float4* wsrc = (const float4*)(wTl + ch*32*128);
    float4* wdst = (float4*)w_s;
    wdst[t]     = wsrc[t];
    wdst[t+256] = wsrc[t+256];
    wdst[t+512] = wsrc[t+512];
    wdst[t+768] = wsrc[t+768];
    __syncthreads();
    #pragma unroll 4
    for (int kk=0;kk<32;kk++){
      float2 w2 = *(const float2*)&w_s[kk*128 + jj];
      int kg = ch*32 + kk;
      #pragma unroll
      for (int r=0;r<4;r++){
        float a = a_s[(wv*4+r)*128 + kg];
        acc[r][0] = fmaf(a, w2.x, acc[r][0]);
        acc[r][1] = fmaf(a, w2.y, acc[r][1]);
      }
    }
    __syncthreads();
  }
  float zc0 = 0.f, zc1 = 0.f;
  #pragma unroll
  for (int r=0;r<4;r++){
    int row = i0 + wv*4 + r;
    float e0 = acc[r][0] > 0.f ? acc[r][0] : expm1f(acc[r][0]);
    float e1 = acc[r][1] > 0.f ? acc[r][1] : expm1f(acc[r][1]);
    zc0 += e0; zc1 += e1;
    if (!last)
      hout[(size_t)row*64 + (jj>>1)] = pack_bf2(e0, e1);
  }
  atomicAdd(&zp[jj], zc0); atomicAdd(&zp[jj+1], zc1);
  __syncthreads();
  if (t < 128) atomicAdd(&z[((blockIdx.x&15)<<7) + t], zp[t]);
}

// hz (redundant per block) + wcol fused. Block 0 also publishes hz to global for k_wrowfinal.
__global__ __launch_bounds__(256) void k_hzwcol(const float* __restrict__ z, const float* __restrict__ fc1W,
                     const float* __restrict__ fc1b, float* __restrict__ hzg,
                     const float* __restrict__ Wc, const float* __restrict__ bc,
                     float* __restrict__ wcol){
  __shared__ float zs[128];
  __shared__ float hzs[128];
  int t = threadIdx.x;
  if (t < 128){
    float s = 0.f;
    #pragma unroll
    for (int q=0;q<16;q++) s += z[(q<<7) + t];
    zs[t] = s * (1.0f / (4.0f * (float)NN));
  }
  __syncthreads();
  if (t < 128){
    float acc = fc1b[t];
    const float* wr = &fc1W[t*128];
    #pragma unroll 8
    for (int k=0;k<128;k++)
      acc = fmaf(zs[k], wr[k], acc);
    float h = acc >= 0.f ? acc : 0.2f*acc;
    hzs[t] = h;
    if (blockIdx.x==0) hzg[t] = h;
  }
  __syncthreads();
  int m = blockIdx.x*256 + t; // < 2048
  float acc = bc[m];
  const float* wr = &Wc[(size_t)m*128];
  #pragma unroll 8
  for (int k=0;k<128;k++)
    acc = fmaf(hzs[k], wr[k], acc);
  wcol[m] = acc;
}

// ---------------- fused wrow+final: one wave per node ----------------
// wave computes wrow[i*16..+15] from fcrow_W (8KB contiguous), then out[i] = ini[i]*(1+wrow·wcol)
__global__ __launch_bounds__(256) void k_wrowfinal(const float* __restrict__ hz, const float* __restrict__ W,
                        const float* __restrict__ b, const float* __restrict__ wcol,
                        const float* __restrict__ ini, float* __restrict__ out){
  __shared__ float wc[16*128];
  int t = threadIdx.x;
  ((float4*)wc)[t] = ((const float4*)wcol)[t];
  ((float4*)wc)[t+256] = ((const float4*)wcol)[t+256];
  __syncthreads();
  int lane = t & 63;
  int i = (blockIdx.x*256 + t) >> 6;   // node id; grid = NN/4 blocks
  int h = lane >> 5;                   // half-wave
  int kq = lane & 31;
  float4 hzv = *(const float4*)&hz[kq*4];
  const float4* wp = (const float4*)(W + (size_t)i*16*128);
  const float* bp = b + (size_t)i*16;
  float wr8[8];
  #pragma unroll
  for (int q=0;q<8;q++){
    // float4 index q*64+lane -> float offset q*256+lane*4 -> row r=2q+h, cols kq*4..+3
    float4 wv = wp[q*64 + lane];
    float p = wv.x*hzv.x;
    p = fmaf(wv.y, hzv.y, p);
    p = fmaf(wv.z, hzv.z, p);
    p = fmaf(wv.w, hzv.w, p);
    p += __shfl_xor(p,1); p += __shfl_xor(p,2); p += __shfl_xor(p,4);
    p += __shfl_xor(p,8); p += __shfl_xor(p,16);
    wr8[q] = p + bp[2*q + h];
  }
  int c = lane*2;
  float a0=0.f, a1=0.f;
  #pragma unroll
  for (int q=0;q<8;q++){
    float we = wr8[q];                    // own r = 2q+h
    float wo = __shfl_xor(wr8[q], 32);    // other half's r = 2q+1-h
    const float2 cA = *(const float2*)&wc[(2*q+h)*128 + c];
    const float2 cB = *(const float2*)&wc[(2*q+1-h)*128 + c];
    a0 = fmaf(we, cA.x, a0); a1 = fmaf(we, cA.y, a1);
    a0 = fmaf(wo, cB.x, a0); a1 = fmaf(wo, cB.y, a1);
  }
  float2 e = *(const float2*)&ini[(size_t)i*128 + c];
  float2 o; o.x = e.x*(1.f+a0); o.y = e.y*(1.f+a1);
  *(float2*)&out[(size_t)i*128 + c] = o;
}

extern "C" void kernel_launch(void* const* d_in, const int* in_sizes, int n_in,
                              void* d_out, int out_size, void* d_ws, size_t ws_size,
                              hipStream_t stream) {
  const int* adj_rows = (const int*)d_in[0];
  const int* adj_cols = (const int*)d_in[1];
  const float* adj_vals = (const float*)d_in[2];
  const float* node_feats = (const float*)d_in[3];
  const float* gnn_W = (const float*)d_in[4];
  const float* gnn_b = (const float*)d_in[5];
  const float* fc1_W = (const float*)d_in[6];
  const float* fc1_b = (const float*)d_in[7];
  const float* fcrow_W = (const float*)d_in[8];
  const float* fcrow_b = (const float*)d_in[9];
  const float* fccol_W = (const float*)d_in[10];
  const float* fccol_b = (const float*)d_in[11];
  const float* ini = (const float*)d_in[12];
  float* out = (float*)d_out;

  char* w = (char*)d_ws;
  auto alloc = [&](size_t bytes)->void*{ void* p = (void*)w; w += (bytes + 255) & ~(size_t)255; return p; };
  // cnt and zb adjacent -> single memset covers both
  int*   cnt    = (int*)  alloc((size_t)NN*4);        // 200000 -> 200192 padded
  float* zb     = (float*)alloc(16*128*4);            // 8192
  u32*   hbf_a  = (u32*)  alloc((size_t)NN*DD*2);
  u32*   hbf_b  = (u32*)  alloc((size_t)NN*DD*2);
  int2*  colval = (int2*) alloc(((size_t)EE + 8*NN + 256)*8);  // padded CSR
  int*   row_ptr= (int*)  alloc((size_t)NN*4);
  int*   cursor = (int*)  alloc((size_t)NN*4);
  int*   bsum   = (int*)  alloc(256*4);
  float* wT     = (float*)alloc(3*128*128*4);
  float* hzb    = (float*)alloc(128*4);
  float* wcolb  = (float*)alloc(2048*4);

  hipMemsetAsync(cnt, 0, ((NN*4 + 255) & ~(size_t)255) + 16*128*4, stream);

  k_hist<<<EE/256, 256, 0, stream>>>(adj_rows, cnt);
  k_scanA<<<256, 256, 0, stream>>>(cnt, bsum);
  k_scanB<<<1, 256, 0, stream>>>(bsum);
  k_scanC<<<256, 256, 0, stream>>>(cnt, bsum, row_ptr, cursor, colval);
  k_scatter<<<EE/256, 256, 0, stream>>>(adj_rows, adj_cols, adj_vals, cursor, colval);
  k_initwT<<<400, 256, 0, stream>>>((const float4*)node_feats, (uint2*)hbf_a, zb, gnn_W, wT);

  const u32* hin = hbf_a; u32* hout = hbf_b;
  for (int l=0; l<LLAYERS; ++l){
    k_layer<<<NN/16, 256, 0, stream>>>(row_ptr, cnt, colval, hin, wT + l*16384,
                                       gnn_b + l*128, hout, zb, (l==LLAYERS-1) ? 1 : 0);
    const u32* tmp = hin; hin = hout; hout = (u32*)tmp;
  }

  k_hzwcol<<<8, 256, 0, stream>>>(zb, fc1_W, fc1_b, hzb, fccol_W, fccol_b, wcolb);
  k_wrowfinal<<<NN/4, 256, 0, stream>>>(hzb, fcrow_W, fcrow_b, wcolb, ini, out);
}